// Round 17
// baseline (246.385 us; speedup 1.0000x reference)
//
#include <hip/hip_runtime.h>
#include <stdint.h>

#define EMB 1024
#define SEQ 2048
#define NB 4
#define NH 16
#define HD 64
#define NGLOB 4
#define WIN 256
#define MTOT (NB*SEQ)   // 8192
#define NQKV (3*EMB)    // 3072

// per-partial: O bf16 [32 q][64 d] (4096 B) + m[32] f32 + l[32] f32 (256 B)
#define PART_U16 2176   // 4352 bytes in u16 units
#define JOBS_PER_BG 260

typedef __attribute__((ext_vector_type(8))) short bf16x8;
typedef __attribute__((ext_vector_type(4))) float f32x4;
typedef __attribute__((ext_vector_type(16))) float f32x16;
typedef unsigned short u16;
typedef unsigned int u32;

#define CL2 0.18033688011112042f  // 0.125 * log2(e)

#if __has_builtin(__builtin_amdgcn_exp2f)
#define EXP2(x) __builtin_amdgcn_exp2f(x)
#else
#define EXP2(x) exp2f(x)
#endif

__device__ __forceinline__ u16 f2bf(float f) {
  u32 u = __builtin_bit_cast(u32, f);
  u += 0x7fffu + ((u >> 16) & 1u);
  return (u16)(u >> 16);
}

__device__ __forceinline__ float bf2f(u16 v) {
  u32 u = (u32)v << 16;
  return __builtin_bit_cast(float, u);
}

// truncating pack of two f32 -> dword of two bf16 (lo = a, hi = b)
__device__ __forceinline__ u32 packtrunc(float a, float b) {
  u32 ua = __builtin_bit_cast(u32, a);
  u32 ub = __builtin_bit_cast(u32, b);
  return (ua >> 16) | (ub & 0xffff0000u);
}

// NOTE: __builtin_amdgcn_permlane32_swap is BANNED this session (R2, R10).
// NOTE: XCD-swizzle on the GEMM grids is BANNED (R13).

#define MFMA16(a, b, c) __builtin_amdgcn_mfma_f32_16x16x32_bf16(a, b, c, 0, 0, 0)
#define MFMA32(a, b, c) __builtin_amdgcn_mfma_f32_32x32x16_bf16(a, b, c, 0, 0, 0)
#define GLD16(g, l) __builtin_amdgcn_global_load_lds( \
    (const __attribute__((address_space(1))) void*)(g), \
    (__attribute__((address_space(3))) void*)(l), 16, 0, 0)

// ---------------- fused prep: cast x + transpose both weights ----------------
// gid < 8192        : cast x fp32 -> bf16 (one float4/thread)
// 8192 <= gid <11264: transpose w_qkv [1024][3072] -> [3072][1024] bf16
// 11264<= gid <12288: transpose w_out [1024][1024] -> [1024][1024] bf16
__global__ void k_prep(const float* __restrict__ x, u16* __restrict__ xb,
                       const float* __restrict__ w_qkv, u16* __restrict__ wqkvT,
                       const float* __restrict__ w_out, u16* __restrict__ woutT) {
  __shared__ float tile[32][33];
  const int gid = blockIdx.x;
  const int tid = threadIdx.x;
  if (gid < 8192) {
    int i = gid * 256 + tid;
    float4 f = ((const float4*)x)[i];
    ushort4 o;
    o.x = f2bf(f.x); o.y = f2bf(f.y); o.z = f2bf(f.z); o.w = f2bf(f.w);
    ((ushort4*)xb)[i] = o;
    return;
  }
  const float* w;
  u16* wt;
  int bx, by, R, C;
  if (gid < 11264) {
    int g2 = gid - 8192;
    bx = g2 % 96; by = g2 / 96; R = EMB; C = NQKV; w = w_qkv; wt = wqkvT;
  } else {
    int g3 = gid - 11264;
    bx = g3 & 31; by = g3 >> 5; R = EMB; C = EMB; w = w_out; wt = woutT;
  }
  const int c0 = bx * 32, r0 = by * 32;
  const int tx = tid & 31, ty = tid >> 5;    // 32 x 8
  #pragma unroll
  for (int j = 0; j < 32; j += 8)
    tile[ty + j][tx] = w[(size_t)(r0 + ty + j) * C + (c0 + tx)];
  __syncthreads();
  #pragma unroll
  for (int j = 0; j < 32; j += 8)
    wt[(size_t)(c0 + ty + j) * R + (r0 + tx)] = f2bf(tile[tx][ty + j]);
}

// ---------------- 128x128 bf16 MFMA GEMM, K=1024, B given transposed -------
template <int EPI>
__global__ __launch_bounds__(256, 2) void k_gemm(
    const u16* __restrict__ A, const u16* __restrict__ Bt,
    const float* __restrict__ bias,
    u16* __restrict__ Qo, u16* __restrict__ Ko, u16* __restrict__ Vt,
    float* __restrict__ outp) {
  __shared__ __align__(16) u16 ldsA[128 * 64];
  __shared__ __align__(16) u16 ldsB[128 * 64];
  const int tid = threadIdx.x;
  const int w = tid >> 6, lane = tid & 63;
  const int wm = w >> 1, wn = w & 1;
  const int m0 = blockIdx.x * 128, n0 = blockIdx.y * 128;
  const int rq = lane & 15, g = lane >> 4;

  const int srow = lane >> 3;
  const int scol = ((lane & 7) ^ srow) << 3;

  f32x4 acc[4][4] = {};
  char* ldsAb = (char*)ldsA;
  char* ldsBb = (char*)ldsB;

  for (int k0 = 0; k0 < EMB; k0 += 64) {
    #pragma unroll
    for (int it = 0; it < 4; ++it) {
      int t = w * 4 + it;
      int row = t * 8 + srow;
      GLD16(A + (size_t)(m0 + row) * EMB + k0 + scol, ldsAb + t * 1024);
      GLD16(Bt + (size_t)(n0 + row) * EMB + k0 + scol, ldsBb + t * 1024);
    }
    __syncthreads();
    #pragma unroll
    for (int ks = 0; ks < 2; ++ks) {
      bf16x8 af[4], bfr[4];
      #pragma unroll
      for (int i = 0; i < 4; ++i) {
        int rowA = wm * 64 + i * 16 + rq;
        int off = (ks * 64 + (g << 4)) ^ ((rowA & 7) << 4);
        af[i] = *(const bf16x8*)(ldsAb + rowA * 128 + off);
        int rowB = wn * 64 + i * 16 + rq;
        int offb = (ks * 64 + (g << 4)) ^ ((rowB & 7) << 4);
        bfr[i] = *(const bf16x8*)(ldsBb + rowB * 128 + offb);
      }
      #pragma unroll
      for (int mi = 0; mi < 4; ++mi)
        #pragma unroll
        for (int ni = 0; ni < 4; ++ni)
          acc[mi][ni] = MFMA16(af[mi], bfr[ni], acc[mi][ni]);
    }
    __syncthreads();
  }

  #pragma unroll
  for (int ni = 0; ni < 4; ++ni) {
    int col = n0 + wn * 64 + ni * 16 + rq;
    float bv = bias[col];
    if (EPI == 0) {
      int part = col >> 10;
      int hh = (col & 1023) >> 6;
      int d = col & 63;
      #pragma unroll
      for (int mi = 0; mi < 4; ++mi) {
        #pragma unroll
        for (int i = 0; i < 4; ++i) {
          int m = m0 + wm * 64 + mi * 16 + g * 4 + i;
          int b = m >> 11, s = m & 2047;
          u16 val = f2bf(acc[mi][ni][i] + bv);
          size_t bh = (size_t)(b * NH + hh);
          if (part == 0)      Qo[(bh * SEQ + s) * HD + d] = val;
          else if (part == 1) Ko[(bh * SEQ + s) * HD + d] = val;
          else                Vt[((bh * 128 + (s >> 4)) * 64 + d) * 16 + (s & 15)] = val;
        }
      }
    } else {
      #pragma unroll
      for (int mi = 0; mi < 4; ++mi)
        #pragma unroll
        for (int i = 0; i < 4; ++i) {
          int m = m0 + wm * 64 + mi * 16 + g * 4 + i;
          outp[(size_t)m * EMB + col] = acc[mi][ni][i] + bv;
        }
    }
  }
}

// ---------------- flash attention pass 1: XCD-clustered wave-jobs ----------
// Explicit K software pipeline: chunk i+1's K issues before chunk i's
// softmax; QK consumes registers loaded one iteration earlier (no K stall).
// PV computes O (lane = d, regs = q); stores row-contiguous.
__global__ __launch_bounds__(256, 4) void k_attn(
    const u16* __restrict__ Q, const u16* __restrict__ K,
    const u16* __restrict__ Vt, u16* __restrict__ ctx,
    u16* __restrict__ part) {
  const int w = threadIdx.x >> 6, lane = threadIdx.x & 63;
  const int l31 = lane & 31;
  const int hi = lane >> 5;
  const bool hib = hi != 0;
  const int hi8 = hi * 8, hi4 = hi * 4;

  const int gid = blockIdx.x;
  const int x = gid & 7;                    // XCD
  const int jb = gid >> 3;                  // 0..225 within XCD
  const bool isglob = jb < 130;

  int bh, qt, cstart, clen, band = 0, slot = 0;
  if (isglob) {
    int pk = jb * 4 + w;                    // 0..519
    int bg = 2 * x + (pk >= JOBS_PER_BG);
    int r = (pk >= JOBS_PER_BG) ? pk - JOBS_PER_BG : pk;
    int b = 0;
    while (b < 7 && r >= 9 * (b + 1) * (b + 2) / 2) ++b;
    band = b;
    int rb = r - 9 * b * (b + 1) / 2;
    int nseg = b + 1;
    if (b == 7) nseg = 8;
    int qoff = rb / nseg;
    int seg = rb - qoff * nseg;
    qt = 9 * b + qoff;
    bh = (bg >> 2) * 16 + (bg & 3);
    slot = bg * JOBS_PER_BG + r;
    int L = qt + 1;
    int base = L / nseg, rm = L - base * nseg;
    clen = base + (seg < rm ? 1 : 0);
    cstart = seg * base + (seg < rm ? seg : rm);
  } else {
    int lj = (jb - 130) * 4 + w;            // 0..383
    int bls = lj >> 6;                      // 0..5
    int bl = 6 * x + bls;                   // 0..47
    qt = lj & 63;
    bh = (bl / 12) * 16 + 4 + (bl % 12);
    int qb_ = qt * 32;
    int klo = (qb_ > WIN) ? qb_ - WIN : 0;
    cstart = klo >> 5;
    clen = qt + 1 - cstart;
  }

  const int qb = qt * 32;
  const int h = bh & 15;
  const int b_ = bh >> 4;
  const bool isloc = !isglob;

  const u16* Qp = Q + (size_t)bh * SEQ * HD;
  const u16* Kp = K + (size_t)bh * SEQ * HD;
  const u16* Vp = Vt + (size_t)bh * SEQ * HD;   // 16-key-blocked layout

  const int q = qb + l31;
  const float NINF = -__builtin_inff();

  bf16x8 qf[4];
  #pragma unroll
  for (int jj = 0; jj < 4; ++jj)
    qf[jj] = *(const bf16x8*)(Qp + (size_t)q * HD + jj * 16 + hi8);

  f32x16 oacc[2] = {};
  float m = NINF;
  float l = 0.f;

  int kc = cstart * 32;
  // prologue: load chunk 0's K
  bf16x8 kc0, kc1, kc2, kc3;
  {
    const u16* Kr = Kp + (size_t)(kc + l31) * HD + hi8;
    kc0 = *(const bf16x8*)(Kr);
    kc1 = *(const bf16x8*)(Kr + 16);
    kc2 = *(const bf16x8*)(Kr + 32);
    kc3 = *(const bf16x8*)(Kr + 48);
  }

  #pragma unroll 2
  for (int it = 0; it < clen; ++it, kc += 32) {
    // V for current chunk (consumed by PV ~600 cyc later)
    bf16x8 vf[2][2];
    {
      const u16* Vb = Vp + (size_t)(kc >> 4) * 1024 + hi8;
      #pragma unroll
      for (int dt = 0; dt < 2; ++dt)
        #pragma unroll
        for (int sl = 0; sl < 2; ++sl)
          vf[dt][sl] = *(const bf16x8*)(Vb + (sl * 64 + dt * 32 + l31) * 16);
    }
    // prefetch next chunk's K (address clamped on last iter -> always valid)
    bf16x8 kn0, kn1, kn2, kn3;
    {
      int kcn = (it + 1 < clen) ? kc + 32 : kc;
      const u16* Kr = Kp + (size_t)(kcn + l31) * HD + hi8;
      kn0 = *(const bf16x8*)(Kr);
      kn1 = *(const bf16x8*)(Kr + 16);
      kn2 = *(const bf16x8*)(Kr + 32);
      kn3 = *(const bf16x8*)(Kr + 48);
    }

    // S^T = K . Q^T with current (previously loaded) K
    f32x16 s = {};
    s = MFMA32(kc0, qf[0], s);
    s = MFMA32(kc1, qf[1], s);
    s = MFMA32(kc2, qf[2], s);
    s = MFMA32(kc3, qf[3], s);

    const bool needs_mask = (kc == qb) || (isloc && (qb - kc > 225));
    float p[16];
    float cmax = NINF;
    if (needs_mask) {
      #pragma unroll
      for (int r = 0; r < 16; ++r) {
        int key = kc + hi4 + (r & 3) + 8 * (r >> 2);
        float v = s[r];
        bool bad = (key > q) || (isloc && (q - key > WIN));
        p[r] = bad ? NINF : v;
        cmax = fmaxf(cmax, p[r]);
      }
    } else {
      #pragma unroll
      for (int r = 0; r < 16; ++r) {
        p[r] = s[r];
        cmax = fmaxf(cmax, p[r]);
      }
    }
    cmax = fmaxf(cmax, __shfl_xor(cmax, 32));

    float muC;
    if (__any(cmax > m + 64.f)) {
      float mn = fmaxf(m, cmax);
      muC = (mn == NINF) ? 0.f : mn * CL2;
      float oldC = (m == NINF) ? muC : m * CL2;
      float f = EXP2(oldC - muC);
      m = mn;
      l *= f;
      #pragma unroll
      for (int r = 0; r < 16; ++r) {
        float fq = __shfl(f, (r & 3) + 8 * (r >> 2) + 4 * hi);
        oacc[0][r] *= fq;
        oacc[1][r] *= fq;
      }
    } else {
      muC = (m == NINF) ? 0.f : m * CL2;
    }

    float psum = 0.f;
    #pragma unroll
    for (int r = 0; r < 16; ++r) {
      float e = EXP2(__builtin_fmaf(p[r], CL2, -muC));
      p[r] = e;
      psum += e;
    }
    psum += __shfl_xor(psum, 32);
    l += psum;

    // P fragments (A-operand)
    union { u32 u[4]; bf16x8 v; } pbf[2];
    #pragma unroll
    for (int sl = 0; sl < 2; ++sl) {
      int s8 = sl * 8;
      u32 X0 = packtrunc(p[s8 + 0], p[s8 + 1]);
      u32 X1 = packtrunc(p[s8 + 2], p[s8 + 3]);
      u32 X2 = packtrunc(p[s8 + 4], p[s8 + 5]);
      u32 X3 = packtrunc(p[s8 + 6], p[s8 + 7]);
      u32 oX0 = (u32)__shfl_xor((int)X0, 32);
      u32 oX1 = (u32)__shfl_xor((int)X1, 32);
      u32 oX2 = (u32)__shfl_xor((int)X2, 32);
      u32 oX3 = (u32)__shfl_xor((int)X3, 32);
      pbf[sl].u[0] = hib ? oX2 : X0;
      pbf[sl].u[1] = hib ? oX3 : X1;
      pbf[sl].u[2] = hib ? X2 : oX0;
      pbf[sl].u[3] = hib ? X3 : oX1;
    }

    // O += P . V  (lane = d, regs = q)
    #pragma unroll
    for (int dt = 0; dt < 2; ++dt)
      #pragma unroll
      for (int sl = 0; sl < 2; ++sl)
        oacc[dt] = MFMA32(pbf[sl].v, vf[dt][sl], oacc[dt]);

    // rotate prefetched K into place
    kc0 = kn0; kc1 = kn1; kc2 = kn2; kc3 = kn3;
  }

  if (isglob && band != 0) {
    // partial: O bf16 [32 q][64 d] + m,l f32 (unnormalized)
    u16* PB = part + (size_t)slot * PART_U16;
    #pragma unroll
    for (int dt = 0; dt < 2; ++dt)
      #pragma unroll
      for (int r = 0; r < 16; ++r) {
        int qoff = (r & 3) + 8 * (r >> 2) + 4 * hi;
        PB[qoff * 64 + dt * 32 + l31] = f2bf(oacc[dt][r]);
      }
    float* PF = (float*)(PB + 2048);
    if (hi == 0) { PF[l31] = m; PF[32 + l31] = l; }
  } else {
    float linv = 1.f / l;
    #pragma unroll
    for (int dt = 0; dt < 2; ++dt) {
      #pragma unroll
      for (int r = 0; r < 16; ++r) {
        int qoff = (r & 3) + 8 * (r >> 2) + 4 * hi;
        float lq = __shfl(linv, qoff);
        ctx[(size_t)(b_ * SEQ + qb + qoff) * EMB + h * HD + dt * 32 + l31] =
            f2bf(oacc[dt][r] * lq);
      }
    }
  }
}

// ---------------- flash attention pass 2: merge nseg partials per task ----
__global__ __launch_bounds__(256, 4) void k_merge(
    const u16* __restrict__ part, u16* __restrict__ ctx) {
  const int t = blockIdx.x;                  // 0..1023: (qt, bg)
  const int bg = t & 15;
  const int qt = t >> 4;
  const int band = qt / 9;                   // 0..7 (qt=63 -> 7)
  const int nseg = (band == 7) ? 8 : band + 1;
  if (band == 0) return;                     // pass 1 wrote ctx directly
  const int jbase = bg * JOBS_PER_BG + 9 * band * (band + 1) / 2
                    + (qt - 9 * band) * nseg;
  const int bh = (bg >> 2) * 16 + (bg & 3);
  const int qb = qt * 32;
  const int h = bh & 15;
  const int bb = bh >> 4;

  const int tid = threadIdx.x;
  const int dd = tid & 63;
  const int qg = tid >> 6;                   // 0..3
  #pragma unroll
  for (int i = 0; i < 8; ++i) {
    int qq = qg * 8 + i;
    float M = -__builtin_inff();
    for (int s = 0; s < nseg; ++s) {
      const float* F = (const float*)(part + (size_t)(jbase + s) * PART_U16 + 2048);
      M = fmaxf(M, F[qq]);
    }
    float L = 0.f, val = 0.f;
    for (int s = 0; s < nseg; ++s) {
      const u16* P = part + (size_t)(jbase + s) * PART_U16;
      const float* F = (const float*)(P + 2048);
      float wgt = EXP2((F[qq] - M) * CL2);
      L += wgt * F[32 + qq];
      val += wgt * bf2f(P[qq * 64 + dd]);
    }
    ctx[(size_t)(bb * SEQ + (qb + qq)) * EMB + h * HD + dd] = f2bf(val / L);
  }
}

extern "C" void kernel_launch(void* const* d_in, const int* in_sizes, int n_in,
                              void* d_out, int out_size, void* d_ws, size_t ws_size,
                              hipStream_t stream) {
  const float* x     = (const float*)d_in[0];
  const float* w_qkv = (const float*)d_in[1];
  const float* b_qkv = (const float*)d_in[2];
  const float* w_out = (const float*)d_in[3];
  const float* b_out = (const float*)d_in[4];
  float* out = (float*)d_out;

  char* ws = (char*)d_ws;
  u16* xb    = (u16*)(ws);                   // 16 MiB (dead after k_gemm<0>)
  u16* wqkvT = (u16*)(ws + (16ull << 20));   // 6 MiB  (dead after k_gemm<0>)
  u16* woutT = (u16*)(ws + (22ull << 20));   // 2 MiB
  u16* Qb    = (u16*)(ws + (24ull << 20));   // 16 MiB
  u16* Kb    = (u16*)(ws + (40ull << 20));   // 16 MiB
  u16* Vt    = (u16*)(ws + (56ull << 20));   // 16 MiB (16-key-blocked layout)
  u16* ctx   = (u16*)(ws + (72ull << 20));   // 16 MiB
  u16* part  = xb;                           // 18.1 MiB partials (xb+wqkvT)

  k_prep<<<dim3(12288), 256, 0, stream>>>(x, xb, w_qkv, wqkvT, w_out, woutT);

  k_gemm<0><<<dim3(MTOT / 128, NQKV / 128), 256, 0, stream>>>(
      xb, wqkvT, b_qkv, Qb, Kb, Vt, nullptr);

  k_attn<<<dim3(226 * 8), 256, 0, stream>>>(Qb, Kb, Vt, ctx, part);
  k_merge<<<dim3(1024), 256, 0, stream>>>(part, ctx);

  k_gemm<1><<<dim3(MTOT / 128, EMB / 128), 256, 0, stream>>>(
      ctx, woutT, b_out, nullptr, nullptr, nullptr, out);
}

// Round 18
// 211.840 us; speedup vs baseline: 1.1631x; 1.1631x over previous
//
#include <hip/hip_runtime.h>
#include <stdint.h>

#define EMB 1024
#define SEQ 2048
#define NB 4
#define NH 16
#define HD 64
#define NGLOB 4
#define WIN 256
#define MTOT (NB*SEQ)   // 8192
#define NQKV (3*EMB)    // 3072

// per-partial: O bf16 [32 q][64 d] (4096 B) + m[32] f32 + l[32] f32 (256 B)
#define PART_U16 2176   // 4352 bytes in u16 units
#define JOBS_PER_BG 260

typedef __attribute__((ext_vector_type(8))) short bf16x8;
typedef __attribute__((ext_vector_type(4))) float f32x4;
typedef __attribute__((ext_vector_type(16))) float f32x16;
typedef unsigned short u16;
typedef unsigned int u32;

#define CL2 0.18033688011112042f  // 0.125 * log2(e)

#if __has_builtin(__builtin_amdgcn_exp2f)
#define EXP2(x) __builtin_amdgcn_exp2f(x)
#else
#define EXP2(x) exp2f(x)
#endif

__device__ __forceinline__ u16 f2bf(float f) {
  u32 u = __builtin_bit_cast(u32, f);
  u += 0x7fffu + ((u >> 16) & 1u);
  return (u16)(u >> 16);
}

__device__ __forceinline__ float bf2f(u16 v) {
  u32 u = (u32)v << 16;
  return __builtin_bit_cast(float, u);
}

// truncating pack of two f32 -> dword of two bf16 (lo = a, hi = b)
__device__ __forceinline__ u32 packtrunc(float a, float b) {
  u32 ua = __builtin_bit_cast(u32, a);
  u32 ub = __builtin_bit_cast(u32, b);
  return (ua >> 16) | (ub & 0xffff0000u);
}

// NOTE: __builtin_amdgcn_permlane32_swap is BANNED this session (R2, R10).
// NOTE: XCD-swizzle on the GEMM grids is BANNED (R13).
// NOTE: register-level K-prefetch in k_attn is BANNED (R17): live ranges
// exceed the 64-VGPR budget at occupancy 4 -> scratch spill, FETCH 3x.

#define MFMA16(a, b, c) __builtin_amdgcn_mfma_f32_16x16x32_bf16(a, b, c, 0, 0, 0)
#define MFMA32(a, b, c) __builtin_amdgcn_mfma_f32_32x32x16_bf16(a, b, c, 0, 0, 0)
#define GLD16(g, l) __builtin_amdgcn_global_load_lds( \
    (const __attribute__((address_space(1))) void*)(g), \
    (__attribute__((address_space(3))) void*)(l), 16, 0, 0)

// ---------------- fused prep: cast x + transpose both weights ----------------
__global__ void k_prep(const float* __restrict__ x, u16* __restrict__ xb,
                       const float* __restrict__ w_qkv, u16* __restrict__ wqkvT,
                       const float* __restrict__ w_out, u16* __restrict__ woutT) {
  __shared__ float tile[32][33];
  const int gid = blockIdx.x;
  const int tid = threadIdx.x;
  if (gid < 8192) {
    int i = gid * 256 + tid;
    float4 f = ((const float4*)x)[i];
    ushort4 o;
    o.x = f2bf(f.x); o.y = f2bf(f.y); o.z = f2bf(f.z); o.w = f2bf(f.w);
    ((ushort4*)xb)[i] = o;
    return;
  }
  const float* w;
  u16* wt;
  int bx, by, R, C;
  if (gid < 11264) {
    int g2 = gid - 8192;
    bx = g2 % 96; by = g2 / 96; R = EMB; C = NQKV; w = w_qkv; wt = wqkvT;
  } else {
    int g3 = gid - 11264;
    bx = g3 & 31; by = g3 >> 5; R = EMB; C = EMB; w = w_out; wt = woutT;
  }
  const int c0 = bx * 32, r0 = by * 32;
  const int tx = tid & 31, ty = tid >> 5;    // 32 x 8
  #pragma unroll
  for (int j = 0; j < 32; j += 8)
    tile[ty + j][tx] = w[(size_t)(r0 + ty + j) * C + (c0 + tx)];
  __syncthreads();
  #pragma unroll
  for (int j = 0; j < 32; j += 8)
    wt[(size_t)(c0 + ty + j) * R + (r0 + tx)] = f2bf(tile[tx][ty + j]);
}

// ---------------- 128x128 bf16 MFMA GEMM, K=1024, B given transposed -------
template <int EPI>
__global__ __launch_bounds__(256, 2) void k_gemm(
    const u16* __restrict__ A, const u16* __restrict__ Bt,
    const float* __restrict__ bias,
    u16* __restrict__ Qo, u16* __restrict__ Ko, u16* __restrict__ Vt,
    float* __restrict__ outp) {
  __shared__ __align__(16) u16 ldsA[128 * 64];
  __shared__ __align__(16) u16 ldsB[128 * 64];
  const int tid = threadIdx.x;
  const int w = tid >> 6, lane = tid & 63;
  const int wm = w >> 1, wn = w & 1;
  const int m0 = blockIdx.x * 128, n0 = blockIdx.y * 128;
  const int rq = lane & 15, g = lane >> 4;

  const int srow = lane >> 3;
  const int scol = ((lane & 7) ^ srow) << 3;

  f32x4 acc[4][4] = {};
  char* ldsAb = (char*)ldsA;
  char* ldsBb = (char*)ldsB;

  for (int k0 = 0; k0 < EMB; k0 += 64) {
    #pragma unroll
    for (int it = 0; it < 4; ++it) {
      int t = w * 4 + it;
      int row = t * 8 + srow;
      GLD16(A + (size_t)(m0 + row) * EMB + k0 + scol, ldsAb + t * 1024);
      GLD16(Bt + (size_t)(n0 + row) * EMB + k0 + scol, ldsBb + t * 1024);
    }
    __syncthreads();
    #pragma unroll
    for (int ks = 0; ks < 2; ++ks) {
      bf16x8 af[4], bfr[4];
      #pragma unroll
      for (int i = 0; i < 4; ++i) {
        int rowA = wm * 64 + i * 16 + rq;
        int off = (ks * 64 + (g << 4)) ^ ((rowA & 7) << 4);
        af[i] = *(const bf16x8*)(ldsAb + rowA * 128 + off);
        int rowB = wn * 64 + i * 16 + rq;
        int offb = (ks * 64 + (g << 4)) ^ ((rowB & 7) << 4);
        bfr[i] = *(const bf16x8*)(ldsBb + rowB * 128 + offb);
      }
      #pragma unroll
      for (int mi = 0; mi < 4; ++mi)
        #pragma unroll
        for (int ni = 0; ni < 4; ++ni)
          acc[mi][ni] = MFMA16(af[mi], bfr[ni], acc[mi][ni]);
    }
    __syncthreads();
  }

  #pragma unroll
  for (int ni = 0; ni < 4; ++ni) {
    int col = n0 + wn * 64 + ni * 16 + rq;
    float bv = bias[col];
    if (EPI == 0) {
      int part = col >> 10;
      int hh = (col & 1023) >> 6;
      int d = col & 63;
      #pragma unroll
      for (int mi = 0; mi < 4; ++mi) {
        #pragma unroll
        for (int i = 0; i < 4; ++i) {
          int m = m0 + wm * 64 + mi * 16 + g * 4 + i;
          int b = m >> 11, s = m & 2047;
          u16 val = f2bf(acc[mi][ni][i] + bv);
          size_t bh = (size_t)(b * NH + hh);
          if (part == 0)      Qo[(bh * SEQ + s) * HD + d] = val;
          else if (part == 1) Ko[(bh * SEQ + s) * HD + d] = val;
          else                Vt[((bh * 128 + (s >> 4)) * 64 + d) * 16 + (s & 15)] = val;
        }
      }
    } else {
      #pragma unroll
      for (int mi = 0; mi < 4; ++mi)
        #pragma unroll
        for (int i = 0; i < 4; ++i) {
          int m = m0 + wm * 64 + mi * 16 + g * 4 + i;
          outp[(size_t)m * EMB + col] = acc[mi][ni][i] + bv;
        }
    }
  }
}

// ---------------- flash attention pass 1: XCD-clustered wave-jobs ----------
// (R16 body — fastest measured: 71.6 us, 64 VGPR, no spill.)
// PV computes O (not O^T): MFMA32(P-frag, V-frag, acc) -> lane = d, regs = q.
__global__ __launch_bounds__(256, 4) void k_attn(
    const u16* __restrict__ Q, const u16* __restrict__ K,
    const u16* __restrict__ Vt, u16* __restrict__ ctx,
    u16* __restrict__ part) {
  const int w = threadIdx.x >> 6, lane = threadIdx.x & 63;
  const int l31 = lane & 31;
  const int hi = lane >> 5;
  const bool hib = hi != 0;
  const int hi8 = hi * 8, hi4 = hi * 4;

  const int gid = blockIdx.x;
  const int x = gid & 7;                    // XCD
  const int jb = gid >> 3;                  // 0..225 within XCD
  const bool isglob = jb < 130;

  int bh, qt, cstart, clen, band = 0, slot = 0;
  if (isglob) {
    int pk = jb * 4 + w;                    // 0..519
    int bg = 2 * x + (pk >= JOBS_PER_BG);
    int r = (pk >= JOBS_PER_BG) ? pk - JOBS_PER_BG : pk;
    int b = 0;
    while (b < 7 && r >= 9 * (b + 1) * (b + 2) / 2) ++b;
    band = b;
    int rb = r - 9 * b * (b + 1) / 2;
    int nseg = b + 1;
    if (b == 7) nseg = 8;
    int qoff = rb / nseg;
    int seg = rb - qoff * nseg;
    qt = 9 * b + qoff;
    bh = (bg >> 2) * 16 + (bg & 3);
    slot = bg * JOBS_PER_BG + r;
    int L = qt + 1;
    int base = L / nseg, rm = L - base * nseg;
    clen = base + (seg < rm ? 1 : 0);
    cstart = seg * base + (seg < rm ? seg : rm);
  } else {
    int lj = (jb - 130) * 4 + w;            // 0..383
    int bls = lj >> 6;                      // 0..5
    int bl = 6 * x + bls;                   // 0..47
    qt = lj & 63;
    bh = (bl / 12) * 16 + 4 + (bl % 12);
    int qb_ = qt * 32;
    int klo = (qb_ > WIN) ? qb_ - WIN : 0;
    cstart = klo >> 5;
    clen = qt + 1 - cstart;
  }

  const int qb = qt * 32;
  const int h = bh & 15;
  const int b_ = bh >> 4;
  const bool isloc = !isglob;

  const u16* Qp = Q + (size_t)bh * SEQ * HD;
  const u16* Kp = K + (size_t)bh * SEQ * HD;
  const u16* Vp = Vt + (size_t)bh * SEQ * HD;   // 16-key-blocked layout

  const int q = qb + l31;
  const float NINF = -__builtin_inff();

  bf16x8 qf[4];
  #pragma unroll
  for (int jj = 0; jj < 4; ++jj)
    qf[jj] = *(const bf16x8*)(Qp + (size_t)q * HD + jj * 16 + hi8);

  f32x16 oacc[2] = {};
  float m = NINF;
  float l = 0.f;

  int kc = cstart * 32;
  #pragma unroll 2
  for (int it = 0; it < clen; ++it, kc += 32) {
    bf16x8 kf0, kf1, kf2, kf3, vf[2][2];
    {
      const u16* Kr = Kp + (size_t)(kc + l31) * HD + hi8;
      kf0 = *(const bf16x8*)(Kr);
      kf1 = *(const bf16x8*)(Kr + 16);
      kf2 = *(const bf16x8*)(Kr + 32);
      kf3 = *(const bf16x8*)(Kr + 48);
      const u16* Vb = Vp + (size_t)(kc >> 4) * 1024 + hi8;
      #pragma unroll
      for (int dt = 0; dt < 2; ++dt)
        #pragma unroll
        for (int sl = 0; sl < 2; ++sl)
          vf[dt][sl] = *(const bf16x8*)(Vb + (sl * 64 + dt * 32 + l31) * 16);
    }

    f32x16 s0 = {}, s1 = {};
    s0 = MFMA32(kf0, qf[0], s0);
    s1 = MFMA32(kf2, qf[2], s1);
    s0 = MFMA32(kf1, qf[1], s0);
    s1 = MFMA32(kf3, qf[3], s1);

    const bool needs_mask = (kc == qb) || (isloc && (qb - kc > 225));
    float p[16];
    float cmax = NINF;
    if (needs_mask) {
      #pragma unroll
      for (int r = 0; r < 16; ++r) {
        int key = kc + hi4 + (r & 3) + 8 * (r >> 2);
        float v = s0[r] + s1[r];
        bool bad = (key > q) || (isloc && (q - key > WIN));
        p[r] = bad ? NINF : v;
        cmax = fmaxf(cmax, p[r]);
      }
    } else {
      #pragma unroll
      for (int r = 0; r < 16; ++r) {
        p[r] = s0[r] + s1[r];
        cmax = fmaxf(cmax, p[r]);
      }
    }
    cmax = fmaxf(cmax, __shfl_xor(cmax, 32));

    float muC;
    if (__any(cmax > m + 64.f)) {
      float mn = fmaxf(m, cmax);
      muC = (mn == NINF) ? 0.f : mn * CL2;
      float oldC = (m == NINF) ? muC : m * CL2;
      float f = EXP2(oldC - muC);
      m = mn;
      l *= f;
      // O rows are queries -> broadcast per-query factor across lanes
      #pragma unroll
      for (int r = 0; r < 16; ++r) {
        float fq = __shfl(f, (r & 3) + 8 * (r >> 2) + 4 * hi);
        oacc[0][r] *= fq;
        oacc[1][r] *= fq;
      }
    } else {
      muC = (m == NINF) ? 0.f : m * CL2;
    }

    float psum = 0.f;
    #pragma unroll
    for (int r = 0; r < 16; ++r) {
      float e = EXP2(__builtin_fmaf(p[r], CL2, -muC));
      p[r] = e;
      psum += e;
    }
    psum += __shfl_xor(psum, 32);
    l += psum;

    // P fragments (A-operand)
    union { u32 u[4]; bf16x8 v; } pbf[2];
    #pragma unroll
    for (int sl = 0; sl < 2; ++sl) {
      int s8 = sl * 8;
      u32 X0 = packtrunc(p[s8 + 0], p[s8 + 1]);
      u32 X1 = packtrunc(p[s8 + 2], p[s8 + 3]);
      u32 X2 = packtrunc(p[s8 + 4], p[s8 + 5]);
      u32 X3 = packtrunc(p[s8 + 6], p[s8 + 7]);
      u32 oX0 = (u32)__shfl_xor((int)X0, 32);
      u32 oX1 = (u32)__shfl_xor((int)X1, 32);
      u32 oX2 = (u32)__shfl_xor((int)X2, 32);
      u32 oX3 = (u32)__shfl_xor((int)X3, 32);
      pbf[sl].u[0] = hib ? oX2 : X0;
      pbf[sl].u[1] = hib ? oX3 : X1;
      pbf[sl].u[2] = hib ? X2 : oX0;
      pbf[sl].u[3] = hib ? X3 : oX1;
    }

    // O += P . V  (lane = d, regs = q)
    #pragma unroll
    for (int dt = 0; dt < 2; ++dt)
      #pragma unroll
      for (int sl = 0; sl < 2; ++sl)
        oacc[dt] = MFMA32(pbf[sl].v, vf[dt][sl], oacc[dt]);
  }

  if (isglob && band != 0) {
    // partial: O bf16 [32 q][64 d] + m,l f32 (unnormalized)
    u16* PB = part + (size_t)slot * PART_U16;
    #pragma unroll
    for (int dt = 0; dt < 2; ++dt)
      #pragma unroll
      for (int r = 0; r < 16; ++r) {
        int qoff = (r & 3) + 8 * (r >> 2) + 4 * hi;
        PB[qoff * 64 + dt * 32 + l31] = f2bf(oacc[dt][r]);
      }
    float* PF = (float*)(PB + 2048);
    if (hi == 0) { PF[l31] = m; PF[32 + l31] = l; }
  } else {
    // direct write: per (dt,r) a 64-lane store covers 2 rows x 64B
    float linv = 1.f / l;
    #pragma unroll
    for (int dt = 0; dt < 2; ++dt) {
      #pragma unroll
      for (int r = 0; r < 16; ++r) {
        int qoff = (r & 3) + 8 * (r >> 2) + 4 * hi;
        float lq = __shfl(linv, qoff);
        ctx[(size_t)(b_ * SEQ + qb + qoff) * EMB + h * HD + dt * 32 + l31] =
            f2bf(oacc[dt][r] * lq);
      }
    }
  }
}

// ---------------- flash attention pass 2: merge nseg partials per task ----
__global__ __launch_bounds__(256, 4) void k_merge(
    const u16* __restrict__ part, u16* __restrict__ ctx) {
  const int t = blockIdx.x;                  // 0..1023: (qt, bg)
  const int bg = t & 15;
  const int qt = t >> 4;
  const int band = qt / 9;                   // 0..7 (qt=63 -> 7)
  const int nseg = (band == 7) ? 8 : band + 1;
  if (band == 0) return;                     // pass 1 wrote ctx directly
  const int jbase = bg * JOBS_PER_BG + 9 * band * (band + 1) / 2
                    + (qt - 9 * band) * nseg;
  const int bh = (bg >> 2) * 16 + (bg & 3);
  const int qb = qt * 32;
  const int h = bh & 15;
  const int bb = bh >> 4;

  const int tid = threadIdx.x;
  const int dd = tid & 63;
  const int qg = tid >> 6;                   // 0..3
  #pragma unroll
  for (int i = 0; i < 8; ++i) {
    int qq = qg * 8 + i;
    float M = -__builtin_inff();
    for (int s = 0; s < nseg; ++s) {
      const float* F = (const float*)(part + (size_t)(jbase + s) * PART_U16 + 2048);
      M = fmaxf(M, F[qq]);
    }
    float L = 0.f, val = 0.f;
    for (int s = 0; s < nseg; ++s) {
      const u16* P = part + (size_t)(jbase + s) * PART_U16;
      const float* F = (const float*)(P + 2048);
      float wgt = EXP2((F[qq] - M) * CL2);
      L += wgt * F[32 + qq];
      val += wgt * bf2f(P[qq * 64 + dd]);
    }
    ctx[(size_t)(bb * SEQ + (qb + qq)) * EMB + h * HD + dd] = f2bf(val / L);
  }
}

extern "C" void kernel_launch(void* const* d_in, const int* in_sizes, int n_in,
                              void* d_out, int out_size, void* d_ws, size_t ws_size,
                              hipStream_t stream) {
  const float* x     = (const float*)d_in[0];
  const float* w_qkv = (const float*)d_in[1];
  const float* b_qkv = (const float*)d_in[2];
  const float* w_out = (const float*)d_in[3];
  const float* b_out = (const float*)d_in[4];
  float* out = (float*)d_out;

  char* ws = (char*)d_ws;
  u16* xb    = (u16*)(ws);                   // 16 MiB (dead after k_gemm<0>)
  u16* wqkvT = (u16*)(ws + (16ull << 20));   // 6 MiB  (dead after k_gemm<0>)
  u16* woutT = (u16*)(ws + (22ull << 20));   // 2 MiB
  u16* Qb    = (u16*)(ws + (24ull << 20));   // 16 MiB
  u16* Kb    = (u16*)(ws + (40ull << 20));   // 16 MiB
  u16* Vt    = (u16*)(ws + (56ull << 20));   // 16 MiB (16-key-blocked layout)
  u16* ctx   = (u16*)(ws + (72ull << 20));   // 16 MiB
  u16* part  = xb;                           // 18.1 MiB partials (xb+wqkvT)

  k_prep<<<dim3(12288), 256, 0, stream>>>(x, xb, w_qkv, wqkvT, w_out, woutT);

  k_gemm<0><<<dim3(MTOT / 128, NQKV / 128), 256, 0, stream>>>(
      xb, wqkvT, b_qkv, Qb, Kb, Vt, nullptr);

  k_attn<<<dim3(226 * 8), 256, 0, stream>>>(Qb, Kb, Vt, ctx, part);
  k_merge<<<dim3(1024), 256, 0, stream>>>(part, ctx);

  k_gemm<1><<<dim3(MTOT / 128, EMB / 128), 256, 0, stream>>>(
      ctx, woutT, b_out, nullptr, nullptr, nullptr, out);
}

// Round 19
// 200.686 us; speedup vs baseline: 1.2277x; 1.0556x over previous
//
#include <hip/hip_runtime.h>
#include <stdint.h>

#define EMB 1024
#define SEQ 2048
#define NB 4
#define NH 16
#define HD 64
#define NGLOB 4
#define WIN 256
#define MTOT (NB*SEQ)   // 8192
#define NQKV (3*EMB)    // 3072

// per-partial: O bf16 [32 q][64 d] (4096 B) + m[32] f32 + l[32] f32 (256 B)
#define PART_U16 2176   // 4352 bytes in u16 units
#define JOBS_PER_BG 260

typedef __attribute__((ext_vector_type(8))) short bf16x8;
typedef __attribute__((ext_vector_type(4))) float f32x4;
typedef __attribute__((ext_vector_type(16))) float f32x16;
typedef unsigned short u16;
typedef unsigned int u32;

#define CL2 0.18033688011112042f  // 0.125 * log2(e)

#if __has_builtin(__builtin_amdgcn_exp2f)
#define EXP2(x) __builtin_amdgcn_exp2f(x)
#else
#define EXP2(x) exp2f(x)
#endif

__device__ __forceinline__ u16 f2bf(float f) {
  u32 u = __builtin_bit_cast(u32, f);
  u += 0x7fffu + ((u >> 16) & 1u);
  return (u16)(u >> 16);
}

__device__ __forceinline__ float bf2f(u16 v) {
  u32 u = (u32)v << 16;
  return __builtin_bit_cast(float, u);
}

// truncating pack of two f32 -> dword of two bf16 (lo = a, hi = b)
__device__ __forceinline__ u32 packtrunc(float a, float b) {
  u32 ua = __builtin_bit_cast(u32, a);
  u32 ub = __builtin_bit_cast(u32, b);
  return (ua >> 16) | (ub & 0xffff0000u);
}

// NOTE: __builtin_amdgcn_permlane32_swap is BANNED this session (R2, R10).
// NOTE: XCD-swizzle on the GEMM grids is BANNED (R13).
// NOTE: HAND-ROTATED register K-prefetch is BANNED (R17: spill at bounds(256,4)).
//       R19 instead relaxes to bounds(256,3) and lets the compiler use the
//       extra VGPR budget for ILP across the unroll-2 iterations.

#define MFMA16(a, b, c) __builtin_amdgcn_mfma_f32_16x16x32_bf16(a, b, c, 0, 0, 0)
#define MFMA32(a, b, c) __builtin_amdgcn_mfma_f32_32x32x16_bf16(a, b, c, 0, 0, 0)
#define GLD16(g, l) __builtin_amdgcn_global_load_lds( \
    (const __attribute__((address_space(1))) void*)(g), \
    (__attribute__((address_space(3))) void*)(l), 16, 0, 0)

// ---------------- fused prep: cast x + transpose both weights ----------------
__global__ void k_prep(const float* __restrict__ x, u16* __restrict__ xb,
                       const float* __restrict__ w_qkv, u16* __restrict__ wqkvT,
                       const float* __restrict__ w_out, u16* __restrict__ woutT) {
  __shared__ float tile[32][33];
  const int gid = blockIdx.x;
  const int tid = threadIdx.x;
  if (gid < 8192) {
    int i = gid * 256 + tid;
    float4 f = ((const float4*)x)[i];
    ushort4 o;
    o.x = f2bf(f.x); o.y = f2bf(f.y); o.z = f2bf(f.z); o.w = f2bf(f.w);
    ((ushort4*)xb)[i] = o;
    return;
  }
  const float* w;
  u16* wt;
  int bx, by, R, C;
  if (gid < 11264) {
    int g2 = gid - 8192;
    bx = g2 % 96; by = g2 / 96; R = EMB; C = NQKV; w = w_qkv; wt = wqkvT;
  } else {
    int g3 = gid - 11264;
    bx = g3 & 31; by = g3 >> 5; R = EMB; C = EMB; w = w_out; wt = woutT;
  }
  const int c0 = bx * 32, r0 = by * 32;
  const int tx = tid & 31, ty = tid >> 5;    // 32 x 8
  #pragma unroll
  for (int j = 0; j < 32; j += 8)
    tile[ty + j][tx] = w[(size_t)(r0 + ty + j) * C + (c0 + tx)];
  __syncthreads();
  #pragma unroll
  for (int j = 0; j < 32; j += 8)
    wt[(size_t)(c0 + ty + j) * R + (r0 + tx)] = f2bf(tile[tx][ty + j]);
}

// ---------------- 128x128 bf16 MFMA GEMM, K=1024, B given transposed -------
template <int EPI>
__global__ __launch_bounds__(256, 2) void k_gemm(
    const u16* __restrict__ A, const u16* __restrict__ Bt,
    const float* __restrict__ bias,
    u16* __restrict__ Qo, u16* __restrict__ Ko, u16* __restrict__ Vt,
    float* __restrict__ outp) {
  __shared__ __align__(16) u16 ldsA[128 * 64];
  __shared__ __align__(16) u16 ldsB[128 * 64];
  const int tid = threadIdx.x;
  const int w = tid >> 6, lane = tid & 63;
  const int wm = w >> 1, wn = w & 1;
  const int m0 = blockIdx.x * 128, n0 = blockIdx.y * 128;
  const int rq = lane & 15, g = lane >> 4;

  const int srow = lane >> 3;
  const int scol = ((lane & 7) ^ srow) << 3;

  f32x4 acc[4][4] = {};
  char* ldsAb = (char*)ldsA;
  char* ldsBb = (char*)ldsB;

  for (int k0 = 0; k0 < EMB; k0 += 64) {
    #pragma unroll
    for (int it = 0; it < 4; ++it) {
      int t = w * 4 + it;
      int row = t * 8 + srow;
      GLD16(A + (size_t)(m0 + row) * EMB + k0 + scol, ldsAb + t * 1024);
      GLD16(Bt + (size_t)(n0 + row) * EMB + k0 + scol, ldsBb + t * 1024);
    }
    __syncthreads();
    #pragma unroll
    for (int ks = 0; ks < 2; ++ks) {
      bf16x8 af[4], bfr[4];
      #pragma unroll
      for (int i = 0; i < 4; ++i) {
        int rowA = wm * 64 + i * 16 + rq;
        int off = (ks * 64 + (g << 4)) ^ ((rowA & 7) << 4);
        af[i] = *(const bf16x8*)(ldsAb + rowA * 128 + off);
        int rowB = wn * 64 + i * 16 + rq;
        int offb = (ks * 64 + (g << 4)) ^ ((rowB & 7) << 4);
        bfr[i] = *(const bf16x8*)(ldsBb + rowB * 128 + offb);
      }
      #pragma unroll
      for (int mi = 0; mi < 4; ++mi)
        #pragma unroll
        for (int ni = 0; ni < 4; ++ni)
          acc[mi][ni] = MFMA16(af[mi], bfr[ni], acc[mi][ni]);
    }
    __syncthreads();
  }

  #pragma unroll
  for (int ni = 0; ni < 4; ++ni) {
    int col = n0 + wn * 64 + ni * 16 + rq;
    float bv = bias[col];
    if (EPI == 0) {
      int part = col >> 10;
      int hh = (col & 1023) >> 6;
      int d = col & 63;
      #pragma unroll
      for (int mi = 0; mi < 4; ++mi) {
        #pragma unroll
        for (int i = 0; i < 4; ++i) {
          int m = m0 + wm * 64 + mi * 16 + g * 4 + i;
          int b = m >> 11, s = m & 2047;
          u16 val = f2bf(acc[mi][ni][i] + bv);
          size_t bh = (size_t)(b * NH + hh);
          if (part == 0)      Qo[(bh * SEQ + s) * HD + d] = val;
          else if (part == 1) Ko[(bh * SEQ + s) * HD + d] = val;
          else                Vt[((bh * 128 + (s >> 4)) * 64 + d) * 16 + (s & 15)] = val;
        }
      }
    } else {
      #pragma unroll
      for (int mi = 0; mi < 4; ++mi)
        #pragma unroll
        for (int i = 0; i < 4; ++i) {
          int m = m0 + wm * 64 + mi * 16 + g * 4 + i;
          outp[(size_t)m * EMB + col] = acc[mi][ni][i] + bv;
        }
    }
  }
}

// ---------------- flash attention pass 1: XCD-clustered wave-jobs ----------
// R16 body; __launch_bounds__(256, 3) gives the allocator ~170 VGPR so the
// unroll-2 iterations' K/V loads can overlap (compiler-scheduled ILP).
__global__ __launch_bounds__(256, 3) void k_attn(
    const u16* __restrict__ Q, const u16* __restrict__ K,
    const u16* __restrict__ Vt, u16* __restrict__ ctx,
    u16* __restrict__ part) {
  const int w = threadIdx.x >> 6, lane = threadIdx.x & 63;
  const int l31 = lane & 31;
  const int hi = lane >> 5;
  const bool hib = hi != 0;
  const int hi8 = hi * 8, hi4 = hi * 4;

  const int gid = blockIdx.x;
  const int x = gid & 7;                    // XCD
  const int jb = gid >> 3;                  // 0..225 within XCD
  const bool isglob = jb < 130;

  int bh, qt, cstart, clen, band = 0, slot = 0;
  if (isglob) {
    int pk = jb * 4 + w;                    // 0..519
    int bg = 2 * x + (pk >= JOBS_PER_BG);
    int r = (pk >= JOBS_PER_BG) ? pk - JOBS_PER_BG : pk;
    int b = 0;
    while (b < 7 && r >= 9 * (b + 1) * (b + 2) / 2) ++b;
    band = b;
    int rb = r - 9 * b * (b + 1) / 2;
    int nseg = b + 1;
    if (b == 7) nseg = 8;
    int qoff = rb / nseg;
    int seg = rb - qoff * nseg;
    qt = 9 * b + qoff;
    bh = (bg >> 2) * 16 + (bg & 3);
    slot = bg * JOBS_PER_BG + r;
    int L = qt + 1;
    int base = L / nseg, rm = L - base * nseg;
    clen = base + (seg < rm ? 1 : 0);
    cstart = seg * base + (seg < rm ? seg : rm);
  } else {
    int lj = (jb - 130) * 4 + w;            // 0..383
    int bls = lj >> 6;                      // 0..5
    int bl = 6 * x + bls;                   // 0..47
    qt = lj & 63;
    bh = (bl / 12) * 16 + 4 + (bl % 12);
    int qb_ = qt * 32;
    int klo = (qb_ > WIN) ? qb_ - WIN : 0;
    cstart = klo >> 5;
    clen = qt + 1 - cstart;
  }

  const int qb = qt * 32;
  const int h = bh & 15;
  const int b_ = bh >> 4;
  const bool isloc = !isglob;

  const u16* Qp = Q + (size_t)bh * SEQ * HD;
  const u16* Kp = K + (size_t)bh * SEQ * HD;
  const u16* Vp = Vt + (size_t)bh * SEQ * HD;   // 16-key-blocked layout

  const int q = qb + l31;
  const float NINF = -__builtin_inff();

  bf16x8 qf[4];
  #pragma unroll
  for (int jj = 0; jj < 4; ++jj)
    qf[jj] = *(const bf16x8*)(Qp + (size_t)q * HD + jj * 16 + hi8);

  f32x16 oacc[2] = {};
  float m = NINF;
  float l = 0.f;

  int kc = cstart * 32;
  #pragma unroll 2
  for (int it = 0; it < clen; ++it, kc += 32) {
    bf16x8 kf0, kf1, kf2, kf3, vf[2][2];
    {
      const u16* Kr = Kp + (size_t)(kc + l31) * HD + hi8;
      kf0 = *(const bf16x8*)(Kr);
      kf1 = *(const bf16x8*)(Kr + 16);
      kf2 = *(const bf16x8*)(Kr + 32);
      kf3 = *(const bf16x8*)(Kr + 48);
      const u16* Vb = Vp + (size_t)(kc >> 4) * 1024 + hi8;
      #pragma unroll
      for (int dt = 0; dt < 2; ++dt)
        #pragma unroll
        for (int sl = 0; sl < 2; ++sl)
          vf[dt][sl] = *(const bf16x8*)(Vb + (sl * 64 + dt * 32 + l31) * 16);
    }

    f32x16 s0 = {}, s1 = {};
    s0 = MFMA32(kf0, qf[0], s0);
    s1 = MFMA32(kf2, qf[2], s1);
    s0 = MFMA32(kf1, qf[1], s0);
    s1 = MFMA32(kf3, qf[3], s1);

    const bool needs_mask = (kc == qb) || (isloc && (qb - kc > 225));
    float p[16];
    float cmax = NINF;
    if (needs_mask) {
      #pragma unroll
      for (int r = 0; r < 16; ++r) {
        int key = kc + hi4 + (r & 3) + 8 * (r >> 2);
        float v = s0[r] + s1[r];
        bool bad = (key > q) || (isloc && (q - key > WIN));
        p[r] = bad ? NINF : v;
        cmax = fmaxf(cmax, p[r]);
      }
    } else {
      #pragma unroll
      for (int r = 0; r < 16; ++r) {
        p[r] = s0[r] + s1[r];
        cmax = fmaxf(cmax, p[r]);
      }
    }
    cmax = fmaxf(cmax, __shfl_xor(cmax, 32));

    float muC;
    if (__any(cmax > m + 64.f)) {
      float mn = fmaxf(m, cmax);
      muC = (mn == NINF) ? 0.f : mn * CL2;
      float oldC = (m == NINF) ? muC : m * CL2;
      float f = EXP2(oldC - muC);
      m = mn;
      l *= f;
      // O rows are queries -> broadcast per-query factor across lanes
      #pragma unroll
      for (int r = 0; r < 16; ++r) {
        float fq = __shfl(f, (r & 3) + 8 * (r >> 2) + 4 * hi);
        oacc[0][r] *= fq;
        oacc[1][r] *= fq;
      }
    } else {
      muC = (m == NINF) ? 0.f : m * CL2;
    }

    float psum = 0.f;
    #pragma unroll
    for (int r = 0; r < 16; ++r) {
      float e = EXP2(__builtin_fmaf(p[r], CL2, -muC));
      p[r] = e;
      psum += e;
    }
    psum += __shfl_xor(psum, 32);
    l += psum;

    // P fragments (A-operand)
    union { u32 u[4]; bf16x8 v; } pbf[2];
    #pragma unroll
    for (int sl = 0; sl < 2; ++sl) {
      int s8 = sl * 8;
      u32 X0 = packtrunc(p[s8 + 0], p[s8 + 1]);
      u32 X1 = packtrunc(p[s8 + 2], p[s8 + 3]);
      u32 X2 = packtrunc(p[s8 + 4], p[s8 + 5]);
      u32 X3 = packtrunc(p[s8 + 6], p[s8 + 7]);
      u32 oX0 = (u32)__shfl_xor((int)X0, 32);
      u32 oX1 = (u32)__shfl_xor((int)X1, 32);
      u32 oX2 = (u32)__shfl_xor((int)X2, 32);
      u32 oX3 = (u32)__shfl_xor((int)X3, 32);
      pbf[sl].u[0] = hib ? oX2 : X0;
      pbf[sl].u[1] = hib ? oX3 : X1;
      pbf[sl].u[2] = hib ? X2 : oX0;
      pbf[sl].u[3] = hib ? X3 : oX1;
    }

    // O += P . V  (lane = d, regs = q)
    #pragma unroll
    for (int dt = 0; dt < 2; ++dt)
      #pragma unroll
      for (int sl = 0; sl < 2; ++sl)
        oacc[dt] = MFMA32(pbf[sl].v, vf[dt][sl], oacc[dt]);
  }

  if (isglob && band != 0) {
    // partial: O bf16 [32 q][64 d] + m,l f32 (unnormalized)
    u16* PB = part + (size_t)slot * PART_U16;
    #pragma unroll
    for (int dt = 0; dt < 2; ++dt)
      #pragma unroll
      for (int r = 0; r < 16; ++r) {
        int qoff = (r & 3) + 8 * (r >> 2) + 4 * hi;
        PB[qoff * 64 + dt * 32 + l31] = f2bf(oacc[dt][r]);
      }
    float* PF = (float*)(PB + 2048);
    if (hi == 0) { PF[l31] = m; PF[32 + l31] = l; }
  } else {
    // direct write: per (dt,r) a 64-lane store covers 2 rows x 64B
    float linv = 1.f / l;
    #pragma unroll
    for (int dt = 0; dt < 2; ++dt) {
      #pragma unroll
      for (int r = 0; r < 16; ++r) {
        int qoff = (r & 3) + 8 * (r >> 2) + 4 * hi;
        float lq = __shfl(linv, qoff);
        ctx[(size_t)(b_ * SEQ + qb + qoff) * EMB + h * HD + dt * 32 + l31] =
            f2bf(oacc[dt][r] * lq);
      }
    }
  }
}

// ---------------- flash attention pass 2: merge nseg partials per task ----
__global__ __launch_bounds__(256, 4) void k_merge(
    const u16* __restrict__ part, u16* __restrict__ ctx) {
  const int t = blockIdx.x;                  // 0..1023: (qt, bg)
  const int bg = t & 15;
  const int qt = t >> 4;
  const int band = qt / 9;                   // 0..7 (qt=63 -> 7)
  const int nseg = (band == 7) ? 8 : band + 1;
  if (band == 0) return;                     // pass 1 wrote ctx directly
  const int jbase = bg * JOBS_PER_BG + 9 * band * (band + 1) / 2
                    + (qt - 9 * band) * nseg;
  const int bh = (bg >> 2) * 16 + (bg & 3);
  const int qb = qt * 32;
  const int h = bh & 15;
  const int bb = bh >> 4;

  const int tid = threadIdx.x;
  const int dd = tid & 63;
  const int qg = tid >> 6;                   // 0..3
  #pragma unroll
  for (int i = 0; i < 8; ++i) {
    int qq = qg * 8 + i;
    float M = -__builtin_inff();
    for (int s = 0; s < nseg; ++s) {
      const float* F = (const float*)(part + (size_t)(jbase + s) * PART_U16 + 2048);
      M = fmaxf(M, F[qq]);
    }
    float L = 0.f, val = 0.f;
    for (int s = 0; s < nseg; ++s) {
      const u16* P = part + (size_t)(jbase + s) * PART_U16;
      const float* F = (const float*)(P + 2048);
      float wgt = EXP2((F[qq] - M) * CL2);
      L += wgt * F[32 + qq];
      val += wgt * bf2f(P[qq * 64 + dd]);
    }
    ctx[(size_t)(bb * SEQ + (qb + qq)) * EMB + h * HD + dd] = f2bf(val / L);
  }
}

extern "C" void kernel_launch(void* const* d_in, const int* in_sizes, int n_in,
                              void* d_out, int out_size, void* d_ws, size_t ws_size,
                              hipStream_t stream) {
  const float* x     = (const float*)d_in[0];
  const float* w_qkv = (const float*)d_in[1];
  const float* b_qkv = (const float*)d_in[2];
  const float* w_out = (const float*)d_in[3];
  const float* b_out = (const float*)d_in[4];
  float* out = (float*)d_out;

  char* ws = (char*)d_ws;
  u16* xb    = (u16*)(ws);                   // 16 MiB (dead after k_gemm<0>)
  u16* wqkvT = (u16*)(ws + (16ull << 20));   // 6 MiB  (dead after k_gemm<0>)
  u16* woutT = (u16*)(ws + (22ull << 20));   // 2 MiB
  u16* Qb    = (u16*)(ws + (24ull << 20));   // 16 MiB
  u16* Kb    = (u16*)(ws + (40ull << 20));   // 16 MiB
  u16* Vt    = (u16*)(ws + (56ull << 20));   // 16 MiB (16-key-blocked layout)
  u16* ctx   = (u16*)(ws + (72ull << 20));   // 16 MiB
  u16* part  = xb;                           // 18.1 MiB partials (xb+wqkvT)

  k_prep<<<dim3(12288), 256, 0, stream>>>(x, xb, w_qkv, wqkvT, w_out, woutT);

  k_gemm<0><<<dim3(MTOT / 128, NQKV / 128), 256, 0, stream>>>(
      xb, wqkvT, b_qkv, Qb, Kb, Vt, nullptr);

  k_attn<<<dim3(226 * 8), 256, 0, stream>>>(Qb, Kb, Vt, ctx, part);
  k_merge<<<dim3(1024), 256, 0, stream>>>(part, ctx);

  k_gemm<1><<<dim3(MTOT / 128, EMB / 128), 256, 0, stream>>>(
      ctx, woutT, b_out, nullptr, nullptr, nullptr, out);
}

// Round 20
// 200.576 us; speedup vs baseline: 1.2284x; 1.0005x over previous
//
#include <hip/hip_runtime.h>
#include <stdint.h>

#define EMB 1024
#define SEQ 2048
#define NB 4
#define NH 16
#define HD 64
#define NGLOB 4
#define WIN 256
#define MTOT (NB*SEQ)   // 8192
#define NQKV (3*EMB)    // 3072

// per-partial: O bf16 [32 q][64 d] (4096 B) + m[32] f32 + l[32] f32 (256 B)
#define PART_U16 2176   // 4352 bytes in u16 units
#define JOBS_PER_BG 260

typedef __attribute__((ext_vector_type(8))) short bf16x8;
typedef __attribute__((ext_vector_type(4))) float f32x4;
typedef __attribute__((ext_vector_type(16))) float f32x16;
typedef unsigned short u16;
typedef unsigned int u32;

#define CL2 0.18033688011112042f  // 0.125 * log2(e)

#if __has_builtin(__builtin_amdgcn_exp2f)
#define EXP2(x) __builtin_amdgcn_exp2f(x)
#else
#define EXP2(x) exp2f(x)
#endif

__device__ __forceinline__ u16 f2bf(float f) {
  u32 u = __builtin_bit_cast(u32, f);
  u += 0x7fffu + ((u >> 16) & 1u);
  return (u16)(u >> 16);
}

__device__ __forceinline__ float bf2f(u16 v) {
  u32 u = (u32)v << 16;
  return __builtin_bit_cast(float, u);
}

// truncating pack of two f32 -> dword of two bf16 (lo = a, hi = b)
__device__ __forceinline__ u32 packtrunc(float a, float b) {
  u32 ua = __builtin_bit_cast(u32, a);
  u32 ub = __builtin_bit_cast(u32, b);
  return (ua >> 16) | (ub & 0xffff0000u);
}

// NOTE: __builtin_amdgcn_permlane32_swap is BANNED this session (R2, R10).
// NOTE: XCD-swizzle on the GEMM grids is BANNED (R13).
// NOTE: HAND-ROTATED register K-prefetch is BANNED (R17: spill).
//       R19 (256,3) freed VGPR budget -> compiler ILP won; R20 relaxes one
//       more step to (256,2). Spill tripwire: FETCH must stay ~36 MB.

#define MFMA16(a, b, c) __builtin_amdgcn_mfma_f32_16x16x32_bf16(a, b, c, 0, 0, 0)
#define MFMA32(a, b, c) __builtin_amdgcn_mfma_f32_32x32x16_bf16(a, b, c, 0, 0, 0)
#define GLD16(g, l) __builtin_amdgcn_global_load_lds( \
    (const __attribute__((address_space(1))) void*)(g), \
    (__attribute__((address_space(3))) void*)(l), 16, 0, 0)

// ---------------- fused prep: cast x + transpose both weights ----------------
__global__ void k_prep(const float* __restrict__ x, u16* __restrict__ xb,
                       const float* __restrict__ w_qkv, u16* __restrict__ wqkvT,
                       const float* __restrict__ w_out, u16* __restrict__ woutT) {
  __shared__ float tile[32][33];
  const int gid = blockIdx.x;
  const int tid = threadIdx.x;
  if (gid < 8192) {
    int i = gid * 256 + tid;
    float4 f = ((const float4*)x)[i];
    ushort4 o;
    o.x = f2bf(f.x); o.y = f2bf(f.y); o.z = f2bf(f.z); o.w = f2bf(f.w);
    ((ushort4*)xb)[i] = o;
    return;
  }
  const float* w;
  u16* wt;
  int bx, by, R, C;
  if (gid < 11264) {
    int g2 = gid - 8192;
    bx = g2 % 96; by = g2 / 96; R = EMB; C = NQKV; w = w_qkv; wt = wqkvT;
  } else {
    int g3 = gid - 11264;
    bx = g3 & 31; by = g3 >> 5; R = EMB; C = EMB; w = w_out; wt = woutT;
  }
  const int c0 = bx * 32, r0 = by * 32;
  const int tx = tid & 31, ty = tid >> 5;    // 32 x 8
  #pragma unroll
  for (int j = 0; j < 32; j += 8)
    tile[ty + j][tx] = w[(size_t)(r0 + ty + j) * C + (c0 + tx)];
  __syncthreads();
  #pragma unroll
  for (int j = 0; j < 32; j += 8)
    wt[(size_t)(c0 + ty + j) * R + (r0 + tx)] = f2bf(tile[tx][ty + j]);
}

// ---------------- 128x128 bf16 MFMA GEMM, K=1024, B given transposed -------
template <int EPI>
__global__ __launch_bounds__(256, 2) void k_gemm(
    const u16* __restrict__ A, const u16* __restrict__ Bt,
    const float* __restrict__ bias,
    u16* __restrict__ Qo, u16* __restrict__ Ko, u16* __restrict__ Vt,
    float* __restrict__ outp) {
  __shared__ __align__(16) u16 ldsA[128 * 64];
  __shared__ __align__(16) u16 ldsB[128 * 64];
  const int tid = threadIdx.x;
  const int w = tid >> 6, lane = tid & 63;
  const int wm = w >> 1, wn = w & 1;
  const int m0 = blockIdx.x * 128, n0 = blockIdx.y * 128;
  const int rq = lane & 15, g = lane >> 4;

  const int srow = lane >> 3;
  const int scol = ((lane & 7) ^ srow) << 3;

  f32x4 acc[4][4] = {};
  char* ldsAb = (char*)ldsA;
  char* ldsBb = (char*)ldsB;

  for (int k0 = 0; k0 < EMB; k0 += 64) {
    #pragma unroll
    for (int it = 0; it < 4; ++it) {
      int t = w * 4 + it;
      int row = t * 8 + srow;
      GLD16(A + (size_t)(m0 + row) * EMB + k0 + scol, ldsAb + t * 1024);
      GLD16(Bt + (size_t)(n0 + row) * EMB + k0 + scol, ldsBb + t * 1024);
    }
    __syncthreads();
    #pragma unroll
    for (int ks = 0; ks < 2; ++ks) {
      bf16x8 af[4], bfr[4];
      #pragma unroll
      for (int i = 0; i < 4; ++i) {
        int rowA = wm * 64 + i * 16 + rq;
        int off = (ks * 64 + (g << 4)) ^ ((rowA & 7) << 4);
        af[i] = *(const bf16x8*)(ldsAb + rowA * 128 + off);
        int rowB = wn * 64 + i * 16 + rq;
        int offb = (ks * 64 + (g << 4)) ^ ((rowB & 7) << 4);
        bfr[i] = *(const bf16x8*)(ldsBb + rowB * 128 + offb);
      }
      #pragma unroll
      for (int mi = 0; mi < 4; ++mi)
        #pragma unroll
        for (int ni = 0; ni < 4; ++ni)
          acc[mi][ni] = MFMA16(af[mi], bfr[ni], acc[mi][ni]);
    }
    __syncthreads();
  }

  #pragma unroll
  for (int ni = 0; ni < 4; ++ni) {
    int col = n0 + wn * 64 + ni * 16 + rq;
    float bv = bias[col];
    if (EPI == 0) {
      int part = col >> 10;
      int hh = (col & 1023) >> 6;
      int d = col & 63;
      #pragma unroll
      for (int mi = 0; mi < 4; ++mi) {
        #pragma unroll
        for (int i = 0; i < 4; ++i) {
          int m = m0 + wm * 64 + mi * 16 + g * 4 + i;
          int b = m >> 11, s = m & 2047;
          u16 val = f2bf(acc[mi][ni][i] + bv);
          size_t bh = (size_t)(b * NH + hh);
          if (part == 0)      Qo[(bh * SEQ + s) * HD + d] = val;
          else if (part == 1) Ko[(bh * SEQ + s) * HD + d] = val;
          else                Vt[((bh * 128 + (s >> 4)) * 64 + d) * 16 + (s & 15)] = val;
        }
      }
    } else {
      #pragma unroll
      for (int mi = 0; mi < 4; ++mi)
        #pragma unroll
        for (int i = 0; i < 4; ++i) {
          int m = m0 + wm * 64 + mi * 16 + g * 4 + i;
          outp[(size_t)m * EMB + col] = acc[mi][ni][i] + bv;
        }
    }
  }
}

// ---------------- flash attention pass 1: XCD-clustered wave-jobs ----------
// R16 body; __launch_bounds__(256, 2) gives the allocator up to ~256 VGPR so
// the unroll-2 iterations' K/V loads can overlap (compiler-scheduled ILP).
__global__ __launch_bounds__(256, 2) void k_attn(
    const u16* __restrict__ Q, const u16* __restrict__ K,
    const u16* __restrict__ Vt, u16* __restrict__ ctx,
    u16* __restrict__ part) {
  const int w = threadIdx.x >> 6, lane = threadIdx.x & 63;
  const int l31 = lane & 31;
  const int hi = lane >> 5;
  const bool hib = hi != 0;
  const int hi8 = hi * 8, hi4 = hi * 4;

  const int gid = blockIdx.x;
  const int x = gid & 7;                    // XCD
  const int jb = gid >> 3;                  // 0..225 within XCD
  const bool isglob = jb < 130;

  int bh, qt, cstart, clen, band = 0, slot = 0;
  if (isglob) {
    int pk = jb * 4 + w;                    // 0..519
    int bg = 2 * x + (pk >= JOBS_PER_BG);
    int r = (pk >= JOBS_PER_BG) ? pk - JOBS_PER_BG : pk;
    int b = 0;
    while (b < 7 && r >= 9 * (b + 1) * (b + 2) / 2) ++b;
    band = b;
    int rb = r - 9 * b * (b + 1) / 2;
    int nseg = b + 1;
    if (b == 7) nseg = 8;
    int qoff = rb / nseg;
    int seg = rb - qoff * nseg;
    qt = 9 * b + qoff;
    bh = (bg >> 2) * 16 + (bg & 3);
    slot = bg * JOBS_PER_BG + r;
    int L = qt + 1;
    int base = L / nseg, rm = L - base * nseg;
    clen = base + (seg < rm ? 1 : 0);
    cstart = seg * base + (seg < rm ? seg : rm);
  } else {
    int lj = (jb - 130) * 4 + w;            // 0..383
    int bls = lj >> 6;                      // 0..5
    int bl = 6 * x + bls;                   // 0..47
    qt = lj & 63;
    bh = (bl / 12) * 16 + 4 + (bl % 12);
    int qb_ = qt * 32;
    int klo = (qb_ > WIN) ? qb_ - WIN : 0;
    cstart = klo >> 5;
    clen = qt + 1 - cstart;
  }

  const int qb = qt * 32;
  const int h = bh & 15;
  const int b_ = bh >> 4;
  const bool isloc = !isglob;

  const u16* Qp = Q + (size_t)bh * SEQ * HD;
  const u16* Kp = K + (size_t)bh * SEQ * HD;
  const u16* Vp = Vt + (size_t)bh * SEQ * HD;   // 16-key-blocked layout

  const int q = qb + l31;
  const float NINF = -__builtin_inff();

  bf16x8 qf[4];
  #pragma unroll
  for (int jj = 0; jj < 4; ++jj)
    qf[jj] = *(const bf16x8*)(Qp + (size_t)q * HD + jj * 16 + hi8);

  f32x16 oacc[2] = {};
  float m = NINF;
  float l = 0.f;

  int kc = cstart * 32;
  #pragma unroll 2
  for (int it = 0; it < clen; ++it, kc += 32) {
    bf16x8 kf0, kf1, kf2, kf3, vf[2][2];
    {
      const u16* Kr = Kp + (size_t)(kc + l31) * HD + hi8;
      kf0 = *(const bf16x8*)(Kr);
      kf1 = *(const bf16x8*)(Kr + 16);
      kf2 = *(const bf16x8*)(Kr + 32);
      kf3 = *(const bf16x8*)(Kr + 48);
      const u16* Vb = Vp + (size_t)(kc >> 4) * 1024 + hi8;
      #pragma unroll
      for (int dt = 0; dt < 2; ++dt)
        #pragma unroll
        for (int sl = 0; sl < 2; ++sl)
          vf[dt][sl] = *(const bf16x8*)(Vb + (sl * 64 + dt * 32 + l31) * 16);
    }

    f32x16 s0 = {}, s1 = {};
    s0 = MFMA32(kf0, qf[0], s0);
    s1 = MFMA32(kf2, qf[2], s1);
    s0 = MFMA32(kf1, qf[1], s0);
    s1 = MFMA32(kf3, qf[3], s1);

    const bool needs_mask = (kc == qb) || (isloc && (qb - kc > 225));
    float p[16];
    float cmax = NINF;
    if (needs_mask) {
      #pragma unroll
      for (int r = 0; r < 16; ++r) {
        int key = kc + hi4 + (r & 3) + 8 * (r >> 2);
        float v = s0[r] + s1[r];
        bool bad = (key > q) || (isloc && (q - key > WIN));
        p[r] = bad ? NINF : v;
        cmax = fmaxf(cmax, p[r]);
      }
    } else {
      #pragma unroll
      for (int r = 0; r < 16; ++r) {
        p[r] = s0[r] + s1[r];
        cmax = fmaxf(cmax, p[r]);
      }
    }
    cmax = fmaxf(cmax, __shfl_xor(cmax, 32));

    float muC;
    if (__any(cmax > m + 64.f)) {
      float mn = fmaxf(m, cmax);
      muC = (mn == NINF) ? 0.f : mn * CL2;
      float oldC = (m == NINF) ? muC : m * CL2;
      float f = EXP2(oldC - muC);
      m = mn;
      l *= f;
      // O rows are queries -> broadcast per-query factor across lanes
      #pragma unroll
      for (int r = 0; r < 16; ++r) {
        float fq = __shfl(f, (r & 3) + 8 * (r >> 2) + 4 * hi);
        oacc[0][r] *= fq;
        oacc[1][r] *= fq;
      }
    } else {
      muC = (m == NINF) ? 0.f : m * CL2;
    }

    float psum = 0.f;
    #pragma unroll
    for (int r = 0; r < 16; ++r) {
      float e = EXP2(__builtin_fmaf(p[r], CL2, -muC));
      p[r] = e;
      psum += e;
    }
    psum += __shfl_xor(psum, 32);
    l += psum;

    // P fragments (A-operand)
    union { u32 u[4]; bf16x8 v; } pbf[2];
    #pragma unroll
    for (int sl = 0; sl < 2; ++sl) {
      int s8 = sl * 8;
      u32 X0 = packtrunc(p[s8 + 0], p[s8 + 1]);
      u32 X1 = packtrunc(p[s8 + 2], p[s8 + 3]);
      u32 X2 = packtrunc(p[s8 + 4], p[s8 + 5]);
      u32 X3 = packtrunc(p[s8 + 6], p[s8 + 7]);
      u32 oX0 = (u32)__shfl_xor((int)X0, 32);
      u32 oX1 = (u32)__shfl_xor((int)X1, 32);
      u32 oX2 = (u32)__shfl_xor((int)X2, 32);
      u32 oX3 = (u32)__shfl_xor((int)X3, 32);
      pbf[sl].u[0] = hib ? oX2 : X0;
      pbf[sl].u[1] = hib ? oX3 : X1;
      pbf[sl].u[2] = hib ? X2 : oX0;
      pbf[sl].u[3] = hib ? X3 : oX1;
    }

    // O += P . V  (lane = d, regs = q)
    #pragma unroll
    for (int dt = 0; dt < 2; ++dt)
      #pragma unroll
      for (int sl = 0; sl < 2; ++sl)
        oacc[dt] = MFMA32(pbf[sl].v, vf[dt][sl], oacc[dt]);
  }

  if (isglob && band != 0) {
    // partial: O bf16 [32 q][64 d] + m,l f32 (unnormalized)
    u16* PB = part + (size_t)slot * PART_U16;
    #pragma unroll
    for (int dt = 0; dt < 2; ++dt)
      #pragma unroll
      for (int r = 0; r < 16; ++r) {
        int qoff = (r & 3) + 8 * (r >> 2) + 4 * hi;
        PB[qoff * 64 + dt * 32 + l31] = f2bf(oacc[dt][r]);
      }
    float* PF = (float*)(PB + 2048);
    if (hi == 0) { PF[l31] = m; PF[32 + l31] = l; }
  } else {
    // direct write: per (dt,r) a 64-lane store covers 2 rows x 64B
    float linv = 1.f / l;
    #pragma unroll
    for (int dt = 0; dt < 2; ++dt) {
      #pragma unroll
      for (int r = 0; r < 16; ++r) {
        int qoff = (r & 3) + 8 * (r >> 2) + 4 * hi;
        float lq = __shfl(linv, qoff);
        ctx[(size_t)(b_ * SEQ + qb + qoff) * EMB + h * HD + dt * 32 + l31] =
            f2bf(oacc[dt][r] * lq);
      }
    }
  }
}

// ---------------- flash attention pass 2: merge nseg partials per task ----
__global__ __launch_bounds__(256, 4) void k_merge(
    const u16* __restrict__ part, u16* __restrict__ ctx) {
  const int t = blockIdx.x;                  // 0..1023: (qt, bg)
  const int bg = t & 15;
  const int qt = t >> 4;
  const int band = qt / 9;                   // 0..7 (qt=63 -> 7)
  const int nseg = (band == 7) ? 8 : band + 1;
  if (band == 0) return;                     // pass 1 wrote ctx directly
  const int jbase = bg * JOBS_PER_BG + 9 * band * (band + 1) / 2
                    + (qt - 9 * band) * nseg;
  const int bh = (bg >> 2) * 16 + (bg & 3);
  const int qb = qt * 32;
  const int h = bh & 15;
  const int bb = bh >> 4;

  const int tid = threadIdx.x;
  const int dd = tid & 63;
  const int qg = tid >> 6;                   // 0..3
  #pragma unroll
  for (int i = 0; i < 8; ++i) {
    int qq = qg * 8 + i;
    float M = -__builtin_inff();
    for (int s = 0; s < nseg; ++s) {
      const float* F = (const float*)(part + (size_t)(jbase + s) * PART_U16 + 2048);
      M = fmaxf(M, F[qq]);
    }
    float L = 0.f, val = 0.f;
    for (int s = 0; s < nseg; ++s) {
      const u16* P = part + (size_t)(jbase + s) * PART_U16;
      const float* F = (const float*)(P + 2048);
      float wgt = EXP2((F[qq] - M) * CL2);
      L += wgt * F[32 + qq];
      val += wgt * bf2f(P[qq * 64 + dd]);
    }
    ctx[(size_t)(bb * SEQ + (qb + qq)) * EMB + h * HD + dd] = f2bf(val / L);
  }
}

extern "C" void kernel_launch(void* const* d_in, const int* in_sizes, int n_in,
                              void* d_out, int out_size, void* d_ws, size_t ws_size,
                              hipStream_t stream) {
  const float* x     = (const float*)d_in[0];
  const float* w_qkv = (const float*)d_in[1];
  const float* b_qkv = (const float*)d_in[2];
  const float* w_out = (const float*)d_in[3];
  const float* b_out = (const float*)d_in[4];
  float* out = (float*)d_out;

  char* ws = (char*)d_ws;
  u16* xb    = (u16*)(ws);                   // 16 MiB (dead after k_gemm<0>)
  u16* wqkvT = (u16*)(ws + (16ull << 20));   // 6 MiB  (dead after k_gemm<0>)
  u16* woutT = (u16*)(ws + (22ull << 20));   // 2 MiB
  u16* Qb    = (u16*)(ws + (24ull << 20));   // 16 MiB
  u16* Kb    = (u16*)(ws + (40ull << 20));   // 16 MiB
  u16* Vt    = (u16*)(ws + (56ull << 20));   // 16 MiB (16-key-blocked layout)
  u16* ctx   = (u16*)(ws + (72ull << 20));   // 16 MiB
  u16* part  = xb;                           // 18.1 MiB partials (xb+wqkvT)

  k_prep<<<dim3(12288), 256, 0, stream>>>(x, xb, w_qkv, wqkvT, w_out, woutT);

  k_gemm<0><<<dim3(MTOT / 128, NQKV / 128), 256, 0, stream>>>(
      xb, wqkvT, b_qkv, Qb, Kb, Vt, nullptr);

  k_attn<<<dim3(226 * 8), 256, 0, stream>>>(Qb, Kb, Vt, ctx, part);
  k_merge<<<dim3(1024), 256, 0, stream>>>(part, ctx);

  k_gemm<1><<<dim3(MTOT / 128, EMB / 128), 256, 0, stream>>>(
      ctx, woutT, b_out, nullptr, nullptr, nullptr, out);
}